// Round 1
// baseline (147267.310 us; speedup 1.0000x reference)
//
#include <hip/hip_runtime.h>
#include <math.h>

#define Hn 1024
#define Gn 4096   // 4*H
#define Bn 64
#define Tn 512
#define Vn 128

__device__ __forceinline__ float sigf(float x) { return 1.0f / (1.0f + expf(-x)); }

// dst[(nb+i)*dstride + doff + kb + tx] = src[(kb+tx... ] transpose: dst[n][k] = src[k][n]
// src is K x N row-major; grid = (N/32, K/32), block = (32,8)
__global__ void tr_kernel(const float* __restrict__ src, float* __restrict__ dst,
                          int N, int dstride, int doff) {
  __shared__ float tile[32][33];
  int kb = blockIdx.y * 32, nb = blockIdx.x * 32;
  int tx = threadIdx.x, ty = threadIdx.y;
  for (int i = ty; i < 32; i += 8)
    tile[i][tx] = src[(size_t)(kb + i) * N + nb + tx];
  __syncthreads();
  for (int i = ty; i < 32; i += 8)
    dst[(size_t)(nb + i) * dstride + doff + kb + tx] = tile[tx][i];
}

// EW0[v][n] = sum_k embed[v][k]*Wx0[k][n] + b0[n]   (V x G)
// grid = (G/256, V/8), block=256
__global__ void ew0_kernel(const float* __restrict__ embed, const float* __restrict__ Wx0,
                           const float* __restrict__ bias, float* __restrict__ EW0) {
  int n = blockIdx.x * 256 + threadIdx.x;
  int vb = blockIdx.y * 8;
  float acc[8] = {0, 0, 0, 0, 0, 0, 0, 0};
  for (int k = 0; k < Hn; k++) {
    float w = Wx0[(size_t)k * Gn + n];
#pragma unroll
    for (int i = 0; i < 8; i++)
      acc[i] = fmaf(embed[(vb + i) * Hn + k], w, acc[i]);
  }
  float bb = bias[n];
#pragma unroll
  for (int i = 0; i < 8; i++)
    EW0[(size_t)(vb + i) * Gn + n] = acc[i] + bb;
}

// Pipelined phase kernel. Phase p:
//   sub-A (bid 0..255):   layer0 step p      (active p in [0,512))
//   sub-B (bid 256..767): layer1 step p-1    (active p in [1,513))
//   sub-C (bid 768..775): output proj step p-2 (active p in [2,514))
// h0 slots: h0(t) in slot t&1.  h1(t) in slot t&1 (written by sub-B at phase t+1).
__global__ __launch_bounds__(256)
void phase_kernel(int p, const int* __restrict__ idx,
                  const float* __restrict__ EW0, const float* __restrict__ Wh0t,
                  const float* __restrict__ W1t, const float* __restrict__ WoutT,
                  const float* __restrict__ bias,
                  float* __restrict__ h0, float* __restrict__ c0,
                  float* __restrict__ h1, float* __restrict__ c1,
                  float* __restrict__ out) {
  __shared__ float gl[64][17];
  const int bid = blockIdx.x, tid = threadIdx.x;
  const int sl_new = p & 1, sl_old = (p + 1) & 1;

  if (bid < 256) {
    // ---- layer0, step p: gates[b][col] = EW0[idx[b][p]][col] + sum_k h0(p-1)[b][k]*Wh0[k][col]
    if (p >= Tn) return;
    const int jb = bid * 4;              // 4 h-cols per WG
    const int cg = tid & 15, rg = tid >> 4;
    const int g = cg >> 2, jo = cg & 3;  // gate group, col offset
    const int col = g * Hn + jb + jo;    // 16 gate-cols per WG
    const int r0 = rg * 4;               // 4 rows per thread
    const float* h0o = h0 + sl_old * (Bn * Hn);  // h0(p-1)
    const float4* wt = (const float4*)(Wh0t + (size_t)col * Hn);
    const float4* a0 = (const float4*)(h0o + (r0 + 0) * Hn);
    const float4* a1 = (const float4*)(h0o + (r0 + 1) * Hn);
    const float4* a2 = (const float4*)(h0o + (r0 + 2) * Hn);
    const float4* a3 = (const float4*)(h0o + (r0 + 3) * Hn);
    float s0 = 0, s1 = 0, s2 = 0, s3 = 0;
    for (int k = 0; k < Hn / 4; k++) {
      float4 w = wt[k];
      float4 x0 = a0[k], x1 = a1[k], x2 = a2[k], x3 = a3[k];
      s0 = fmaf(x0.x, w.x, s0); s0 = fmaf(x0.y, w.y, s0); s0 = fmaf(x0.z, w.z, s0); s0 = fmaf(x0.w, w.w, s0);
      s1 = fmaf(x1.x, w.x, s1); s1 = fmaf(x1.y, w.y, s1); s1 = fmaf(x1.z, w.z, s1); s1 = fmaf(x1.w, w.w, s1);
      s2 = fmaf(x2.x, w.x, s2); s2 = fmaf(x2.y, w.y, s2); s2 = fmaf(x2.z, w.z, s2); s2 = fmaf(x2.w, w.w, s2);
      s3 = fmaf(x3.x, w.x, s3); s3 = fmaf(x3.y, w.y, s3); s3 = fmaf(x3.z, w.z, s3); s3 = fmaf(x3.w, w.w, s3);
    }
    float sv[4] = {s0, s1, s2, s3};
#pragma unroll
    for (int i = 0; i < 4; i++) {
      int r = r0 + i;
      int v = idx[r * Tn + p];
      gl[r][cg] = sv[i] + EW0[(size_t)v * Gn + col];
    }
    __syncthreads();
    {
      int r = tid & 63, jj = tid >> 6;   // 64 rows x 4 h-cols = 256 updates
      int j = jb + jj;
      float ig = gl[r][jj], fg = gl[r][4 + jj], gg = gl[r][8 + jj], og = gl[r][12 + jj];
      float cn = sigf(fg) * c0[r * Hn + j] + sigf(ig) * tanhf(gg);
      float hn = sigf(og) * tanhf(cn);
      c0[r * Hn + j] = cn;
      h0[sl_new * (Bn * Hn) + r * Hn + j] = hn;   // h0(p) -> slot p&1
    }
  } else if (bid < 768) {
    // ---- layer1, step t=p-1: gates = h0(p-1)@Wx1 + h1(p-2)@Wh1 + b1 (K=2048 fused)
    const int t = p - 1;
    if (t < 0 || t >= Tn) return;
    const int wg = bid - 256;
    const int jb = wg * 2;               // 2 h-cols per WG
    const int cg = tid & 7, rg = tid >> 3;
    const int g = cg >> 1, jo = cg & 1;
    const int col = g * Hn + jb + jo;    // 8 gate-cols per WG
    const int r0 = rg * 2;               // 2 rows per thread
    const float* h0c = h0 + sl_old * (Bn * Hn);  // h0(p-1): slot (p-1)&1
    const float* h1o = h1 + sl_new * (Bn * Hn);  // h1(p-2): slot (p-2)&1 = p&1
    const float4* wt = (const float4*)(W1t + (size_t)col * (2 * Hn));
    float s0 = 0, s1 = 0;
    {
      const float4* a0 = (const float4*)(h0c + (r0 + 0) * Hn);
      const float4* a1 = (const float4*)(h0c + (r0 + 1) * Hn);
      for (int k = 0; k < Hn / 4; k++) {
        float4 w = wt[k];
        float4 x0 = a0[k], x1 = a1[k];
        s0 = fmaf(x0.x, w.x, s0); s0 = fmaf(x0.y, w.y, s0); s0 = fmaf(x0.z, w.z, s0); s0 = fmaf(x0.w, w.w, s0);
        s1 = fmaf(x1.x, w.x, s1); s1 = fmaf(x1.y, w.y, s1); s1 = fmaf(x1.z, w.z, s1); s1 = fmaf(x1.w, w.w, s1);
      }
    }
    {
      const float4* a0 = (const float4*)(h1o + (r0 + 0) * Hn);
      const float4* a1 = (const float4*)(h1o + (r0 + 1) * Hn);
      const float4* wt2 = wt + Hn / 4;
      for (int k = 0; k < Hn / 4; k++) {
        float4 w = wt2[k];
        float4 x0 = a0[k], x1 = a1[k];
        s0 = fmaf(x0.x, w.x, s0); s0 = fmaf(x0.y, w.y, s0); s0 = fmaf(x0.z, w.z, s0); s0 = fmaf(x0.w, w.w, s0);
        s1 = fmaf(x1.x, w.x, s1); s1 = fmaf(x1.y, w.y, s1); s1 = fmaf(x1.z, w.z, s1); s1 = fmaf(x1.w, w.w, s1);
      }
    }
    float bb = bias[Gn + col];
    gl[r0][cg] = s0 + bb;
    gl[r0 + 1][cg] = s1 + bb;
    __syncthreads();
    if (tid < 128) {
      int r = tid & 63, jj = tid >> 6;   // 64 rows x 2 h-cols
      int j = jb + jj;
      float ig = gl[r][jj], fg = gl[r][2 + jj], gg = gl[r][4 + jj], og = gl[r][6 + jj];
      float cn = sigf(fg) * c1[r * Hn + j] + sigf(ig) * tanhf(gg);
      float hn = sigf(og) * tanhf(cn);
      c1[r * Hn + j] = cn;
      h1[sl_old * (Bn * Hn) + r * Hn + j] = hn;  // h1(p-1) -> slot (p-1)&1
    }
  } else {
    // ---- output projection for step t=p-2: out[b][t][:] = h1(p-2) @ W_out
    const int t = p - 2;
    if (t < 0 || t >= Tn) return;
    const int wg = bid - 768;            // 8 WGs x 16 out-cols
    const int cb = wg * 16;
    const int cg = tid & 15, rg = tid >> 4;
    const int col = cb + cg;
    const int r0 = rg * 4;
    const float* h1r = h1 + sl_new * (Bn * Hn);  // h1(p-2): slot p&1
    const float4* wt = (const float4*)(WoutT + (size_t)col * Hn);
    const float4* a0 = (const float4*)(h1r + (r0 + 0) * Hn);
    const float4* a1 = (const float4*)(h1r + (r0 + 1) * Hn);
    const float4* a2 = (const float4*)(h1r + (r0 + 2) * Hn);
    const float4* a3 = (const float4*)(h1r + (r0 + 3) * Hn);
    float s0 = 0, s1 = 0, s2 = 0, s3 = 0;
    for (int k = 0; k < Hn / 4; k++) {
      float4 w = wt[k];
      float4 x0 = a0[k], x1 = a1[k], x2 = a2[k], x3 = a3[k];
      s0 = fmaf(x0.x, w.x, s0); s0 = fmaf(x0.y, w.y, s0); s0 = fmaf(x0.z, w.z, s0); s0 = fmaf(x0.w, w.w, s0);
      s1 = fmaf(x1.x, w.x, s1); s1 = fmaf(x1.y, w.y, s1); s1 = fmaf(x1.z, w.z, s1); s1 = fmaf(x1.w, w.w, s1);
      s2 = fmaf(x2.x, w.x, s2); s2 = fmaf(x2.y, w.y, s2); s2 = fmaf(x2.z, w.z, s2); s2 = fmaf(x2.w, w.w, s2);
      s3 = fmaf(x3.x, w.x, s3); s3 = fmaf(x3.y, w.y, s3); s3 = fmaf(x3.z, w.z, s3); s3 = fmaf(x3.w, w.w, s3);
    }
    float sv[4] = {s0, s1, s2, s3};
#pragma unroll
    for (int i = 0; i < 4; i++)
      out[((size_t)(r0 + i) * Tn + t) * Vn + col] = sv[i];
  }
}

extern "C" void kernel_launch(void* const* d_in, const int* in_sizes, int n_in,
                              void* d_out, int out_size, void* d_ws, size_t ws_size,
                              hipStream_t stream) {
  const int* idx = (const int*)d_in[0];        // (B,T) int32
  const float* embed = (const float*)d_in[1];  // (V,H)
  const float* Wx = (const float*)d_in[2];     // (L,H,4H)
  const float* Wh = (const float*)d_in[3];     // (L,H,4H)
  const float* bias = (const float*)d_in[4];   // (L,4H)
  const float* Wout = (const float*)d_in[5];   // (H,V)
  float* out = (float*)d_out;                  // (B,T,V) fp32
  float* ws = (float*)d_ws;

  // workspace layout (floats)
  float* EW0 = ws;                       // 128*4096      = 524288
  float* Wh0t = EW0 + 524288;            // 4096*1024     = 4194304
  float* W1t = Wh0t + 4194304;           // 4096*2048     = 8388608
  float* WoutT = W1t + 8388608;          // 128*1024      = 131072
  float* h0 = WoutT + 131072;            // 2*64*1024     = 131072
  float* h1 = h0 + 131072;               // 2*64*1024     = 131072
  float* c0 = h1 + 131072;               // 64*1024       = 65536
  float* c1 = c0 + 65536;                // 64*1024       = 65536
  // total = 13,631,488 floats = 52 MiB

  // zero states (h0 both slots, h1 both slots, c0, c1 — contiguous)
  hipMemsetAsync(h0, 0, (size_t)(131072 + 131072 + 65536 + 65536) * sizeof(float), stream);

  dim3 tb(32, 8);
  // Wh0^T : (4096,1024)
  tr_kernel<<<dim3(Gn / 32, Hn / 32), tb, 0, stream>>>(Wh, Wh0t, Gn, Hn, 0);
  // W1^T = [Wx1; Wh1]^T : (4096, 2048)
  tr_kernel<<<dim3(Gn / 32, Hn / 32), tb, 0, stream>>>(Wx + (size_t)Hn * Gn, W1t, Gn, 2 * Hn, 0);
  tr_kernel<<<dim3(Gn / 32, Hn / 32), tb, 0, stream>>>(Wh + (size_t)Hn * Gn, W1t, Gn, 2 * Hn, Hn);
  // W_out^T : (128, 1024)
  tr_kernel<<<dim3(Vn / 32, Hn / 32), tb, 0, stream>>>(Wout, WoutT, Vn, Hn, 0);
  // EW0 = embed @ Wx0 + b0
  ew0_kernel<<<dim3(Gn / 256, Vn / 8), 256, 0, stream>>>(embed, Wx, bias, EW0);

  for (int p = 0; p < Tn + 2; p++) {
    phase_kernel<<<776, 256, 0, stream>>>(p, idx, EW0, Wh0t, W1t, WoutT, bias,
                                          h0, c0, h1, c1, out);
  }

  (void)in_sizes; (void)n_in; (void)out_size; (void)ws_size;
}

// Round 2
// 22639.256 us; speedup vs baseline: 6.5050x; 6.5050x over previous
//
#include <hip/hip_runtime.h>
#include <math.h>

#define Hn 1024
#define Gn 4096   // 4*H
#define Bn 64
#define Tn 512
#define Vn 128

typedef short bf16x8 __attribute__((ext_vector_type(8)));
typedef float f32x16 __attribute__((ext_vector_type(16)));
typedef float f32x4 __attribute__((ext_vector_type(4)));

#define MFMA(a, b, c) __builtin_amdgcn_mfma_f32_32x32x16_bf16(a, b, c, 0, 0, 0)

// ---------------- numeric helpers ----------------
__device__ __forceinline__ unsigned short bf_hi(float x) {
  unsigned u = __builtin_bit_cast(unsigned, x);
  return (unsigned short)((u + 0x7fffu + ((u >> 16) & 1u)) >> 16);  // RNE bf16
}
__device__ __forceinline__ float bf_f(unsigned short h) {
  unsigned u = ((unsigned)h) << 16;
  return __builtin_bit_cast(float, u);
}
__device__ __forceinline__ void split3(float x, unsigned short &a, unsigned short &b, unsigned short &c) {
  a = bf_hi(x); float r = x - bf_f(a);
  b = bf_hi(r); r -= bf_f(b);
  c = bf_hi(r);
}
__device__ __forceinline__ float sigf(float x) {
  float e = exp2f(x * -1.442695040888963f);
  return __fdividef(1.f, 1.f + e);
}
__device__ __forceinline__ float tanh_(float x) {
  x = fminf(fmaxf(x, -15.f), 15.f);
  float e = exp2f(x * -2.885390081777926f);
  return __fdividef(1.f - e, 1.f + e);
}

// ---------------- prep: weight fragment packing ----------------
// dst[nt][ks][plane][lane][8] bf16 planes of W[k][col]
// k = ks*16 + (lane>>5)*8 + e ; col = gateIlv ? g*Hn + wg*32 + (lane&31) : nt*32 + (lane&31)
// rows k < K1 from srcA, else srcB (row k-K1). grid = NT*Ksteps blocks x 64 thr.
__global__ void pack_kernel(const float* __restrict__ srcA, const float* __restrict__ srcB,
                            int K1, int Ksteps, int srcN, int gateIlv,
                            unsigned short* __restrict__ dst) {
  int lf = threadIdx.x;
  int ks = blockIdx.x % Ksteps;
  int nt = blockIdx.x / Ksteps;
  int col;
  if (gateIlv) { int wg = nt >> 2, g = nt & 3; col = g * Hn + wg * 32 + (lf & 31); }
  else col = nt * 32 + (lf & 31);
  int k0 = ks * 16 + (lf >> 5) * 8;
  bf16x8 v0, v1, v2;
#pragma unroll
  for (int e = 0; e < 8; e++) {
    int k = k0 + e;
    const float* s = (k < K1) ? srcA + (size_t)k * srcN : srcB + (size_t)(k - K1) * srcN;
    float x = s[col];
    unsigned short a, b, c; split3(x, a, b, c);
    v0[e] = (short)a; v1[e] = (short)b; v2[e] = (short)c;
  }
  size_t base = ((size_t)(nt * Ksteps + ks) * 3) * 512 + (size_t)lf * 8;
  *(bf16x8*)(dst + base)        = v0;
  *(bf16x8*)(dst + base + 512)  = v1;
  *(bf16x8*)(dst + base + 1024) = v2;
}

// EW0[v][n] = sum_k embed[v][k]*Wx0[k][n] + b0[n]   (V x G), fp32
__global__ void ew0_kernel(const float* __restrict__ embed, const float* __restrict__ Wx0,
                           const float* __restrict__ bias, float* __restrict__ EW0) {
  int n = blockIdx.x * 256 + threadIdx.x;
  int vb = blockIdx.y * 8;
  float acc[8] = {0, 0, 0, 0, 0, 0, 0, 0};
  for (int k = 0; k < Hn; k++) {
    float w = Wx0[(size_t)k * Gn + n];
#pragma unroll
    for (int i = 0; i < 8; i++)
      acc[i] = fmaf(embed[(vb + i) * Hn + k], w, acc[i]);
  }
  float bb = bias[n];
#pragma unroll
  for (int i = 0; i < 8; i++)
    EW0[(size_t)(vb + i) * Gn + n] = acc[i] + bb;
}

// ---------------- GEMM phase helpers ----------------
__device__ __forceinline__ void accWrite(const f32x16 (&A)[4], char* base, int l) {
#pragma unroll
  for (int g = 0; g < 4; g++)
#pragma unroll
    for (int q = 0; q < 4; q++) {
      f32x4 v = { A[g][q * 4 + 0], A[g][q * 4 + 1], A[g][q * 4 + 2], A[g][q * 4 + 3] };
      *(f32x4*)(base + (size_t)(g * 4 + q) * 1024 + (size_t)l * 16) = v;
    }
}
__device__ __forceinline__ void accAdd3(f32x16 (&A)[4], char* lds, int l) {
#pragma unroll
  for (int s = 0; s < 3; s++)
#pragma unroll
    for (int g = 0; g < 4; g++)
#pragma unroll
      for (int q = 0; q < 4; q++) {
        f32x4 v = *(f32x4*)(lds + (size_t)s * 16384 + (size_t)(g * 4 + q) * 1024 + (size_t)l * 16);
        A[g][q * 4 + 0] += v[0]; A[g][q * 4 + 1] += v[1];
        A[g][q * 4 + 2] += v[2]; A[g][q * 4 + 3] += v[3];
      }
}
__device__ __forceinline__ void partialWrite(const f32x16 (&A)[4], int mt, int l, float* __restrict__ pp) {
#pragma unroll
  for (int r = 0; r < 16; r++) {
    int b = mt * 32 + (r & 3) + ((r >> 2) << 3) + ((l >> 5) << 2);
#pragma unroll
    for (int g = 0; g < 4; g++)
      pp[(size_t)b * 128 + g * 32 + (l & 31)] = A[g][r];
  }
}
__device__ __forceinline__ void storeOut(const f32x16 (&A)[4], int mt, int l, int t, float* __restrict__ out) {
#pragma unroll
  for (int r = 0; r < 16; r++) {
    int b = mt * 32 + (r & 3) + ((r >> 2) << 3) + ((l >> 5) << 2);
#pragma unroll
    for (int g = 0; g < 4; g++)
      out[((size_t)b * Tn + t) * Vn + g * 32 + (l & 31)] = A[g][r];
  }
}

// ---------------- stage G: GEMM partials ----------------
// grid 193 x 256.  bid<64: layer0 (jb=bid>>1, Khalf=bid&1)
//                  64..191: layer1 (jb=(bid-64)>>2, Kquarter)
//                  192: out-projection (full, in-WG K-split)
// h frag buffers layout: [ks][plane][mt][lane][8] ushort (chunk = 3072 ushort per ks)
__global__ __launch_bounds__(256, 1)
void gemm_phase(int p,
                const unsigned short* __restrict__ W0f, const unsigned short* __restrict__ W1f,
                const unsigned short* __restrict__ Woutf,
                const unsigned short* __restrict__ h0f, const unsigned short* __restrict__ h1f,
                float* __restrict__ pa0, float* __restrict__ pa1, float* __restrict__ out) {
  __shared__ char lds[49152];
  const int bid = blockIdx.x, tid = threadIdx.x;
  const int w = tid >> 6, l = tid & 63;
  int mode, jb, seg, nsteps, Ktot, ks0;
  const unsigned short *Bsrc, *Af;
  if (bid < 64) {
    if (p >= Tn) return;
    mode = 0; jb = bid >> 1; seg = bid & 1; Ktot = 64; nsteps = 8;
    ks0 = seg * 32 + w * 8;
    Bsrc = W0f + (size_t)(jb * 4) * Ktot * 1536;
    Af = h0f;
  } else if (bid < 192) {
    int t = p - 1; if (t < 0 || t >= Tn) return;
    mode = 1; jb = (bid - 64) >> 2; seg = (bid - 64) & 3; Ktot = 128; nsteps = 8;
    ks0 = seg * 32 + w * 8;
    Bsrc = W1f + (size_t)(jb * 4) * Ktot * 1536;
    Af = (seg < 2) ? h0f : h1f;
  } else {
    int t = p - 2; if (t < 0 || t >= Tn) return;
    mode = 2; jb = 0; seg = 0; Ktot = 64; nsteps = 16;
    ks0 = w * 16;
    Bsrc = Woutf; Af = h1f;
  }
  const int aks0 = (mode == 1 && seg >= 2) ? (ks0 - 64) : ks0;

  f32x16 acc[2][4] = {};
#pragma unroll 2
  for (int i = 0; i < nsteps; i++) {
    const int ks = ks0 + i, aks = aks0 + i;
    const unsigned short* ab = Af + (size_t)aks * 3072 + (size_t)l * 8;
    bf16x8 a[3][2];
#pragma unroll
    for (int pl = 0; pl < 3; pl++)
#pragma unroll
      for (int mt = 0; mt < 2; mt++)
        a[pl][mt] = *(const bf16x8*)(ab + (pl * 2 + mt) * 512);
#pragma unroll
    for (int g = 0; g < 4; g++) {
      const unsigned short* bb = Bsrc + ((size_t)g * Ktot + ks) * 1536 + (size_t)l * 8;
      bf16x8 b0 = *(const bf16x8*)bb;
      bf16x8 b1 = *(const bf16x8*)(bb + 512);
      bf16x8 b2 = *(const bf16x8*)(bb + 1024);
#pragma unroll
      for (int mt = 0; mt < 2; mt++) {
        f32x16 t = acc[mt][g];
        t = MFMA(a[0][mt], b0, t);   // hh
        t = MFMA(a[0][mt], b1, t);   // hm
        t = MFMA(a[1][mt], b0, t);   // mh
        t = MFMA(a[1][mt], b1, t);   // mm
        t = MFMA(a[0][mt], b2, t);   // hl
        t = MFMA(a[2][mt], b0, t);   // lh
        acc[mt][g] = t;
      }
    }
  }

  // cross-wave K reduction: shot 0 -> w0 owns mt0, shot 1 -> w1 owns mt1
  __syncthreads();
  if (w != 0) accWrite(acc[0], lds + (size_t)(w - 1) * 16384, l);
  __syncthreads();
  if (w == 0) accAdd3(acc[0], lds, l);
  __syncthreads();
  if (w != 1) accWrite(acc[1], lds + (size_t)((w == 0) ? 0 : (w - 1)) * 16384, l);
  __syncthreads();
  if (w == 1) accAdd3(acc[1], lds, l);

  if (mode == 2) {
    const int t = p - 2;
    if (w == 0) storeOut(acc[0], 0, l, t, out);
    else if (w == 1) storeOut(acc[1], 1, l, t, out);
    return;
  }
  float* pp = (mode == 0) ? (pa0 + (size_t)(jb * 2 + seg) * 8192)
                          : (pa1 + (size_t)(jb * 4 + seg) * 8192);
  if (w == 0) partialWrite(acc[0], 0, l, pp);
  else if (w == 1) partialWrite(acc[1], 1, l, pp);
}

// ---------------- stage U: combine partials + LSTM update + h repack ----------------
// grid 64 x 256. bid<32: layer0 jb=bid (t=p); else layer1 jb=bid-32 (t=p-1)
__global__ __launch_bounds__(256, 1)
void update_phase(int p, const int* __restrict__ idx, const float* __restrict__ EW0,
                  const float* __restrict__ bias,
                  const float* __restrict__ pa0, const float* __restrict__ pa1,
                  unsigned short* __restrict__ h0f, unsigned short* __restrict__ h1f,
                  float* __restrict__ c0t, float* __restrict__ c1t) {
  const int bid = blockIdx.x, tid = threadIdx.x;
  int layer, jb, t;
  if (bid < 32) { layer = 0; jb = bid; t = p; if (t >= Tn) return; }
  else { layer = 1; jb = bid - 32; t = p - 1; if (t < 0 || t >= Tn) return; }
  const int jl = tid & 31, bq = tid >> 5;
  const int j = jb * 32 + jl;
  float* ct = layer ? c1t : c0t;
  unsigned short* hf = layer ? h1f : h0f;
  const float* P = layer ? (pa1 + (size_t)jb * 4 * 8192) : (pa0 + (size_t)jb * 2 * 8192);
  const int nseg = layer ? 4 : 2;
  const int ksj = j >> 4, kh = (j >> 3) & 1, e = j & 7;
#pragma unroll
  for (int bi = 0; bi < 8; bi++) {
    int b = bq * 8 + bi;
    size_t po = (size_t)b * 128 + jl;
    float gi = P[po], gf = P[po + 32], gg = P[po + 64], go = P[po + 96];
    for (int s = 1; s < nseg; s++) {
      const float* Q = P + (size_t)s * 8192;
      gi += Q[po]; gf += Q[po + 32]; gg += Q[po + 64]; go += Q[po + 96];
    }
    if (layer == 0) {
      int v = idx[b * Tn + t];
      const float* er = EW0 + (size_t)v * Gn + j;
      gi += er[0]; gf += er[1024]; gg += er[2048]; go += er[3072];
    } else {
      const float* br = bias + Gn + j;
      gi += br[0]; gf += br[1024]; gg += br[2048]; go += br[3072];
    }
    size_t ci = (size_t)j * 64 + b;
    float cn = sigf(gf) * ct[ci] + sigf(gi) * tanh_(gg);
    float hn = sigf(go) * tanh_(cn);
    ct[ci] = cn;
    unsigned short q0, q1, q2; split3(hn, q0, q1, q2);
    size_t ho = ((size_t)(ksj * 3) * 2 + (b >> 5)) * 512 + (size_t)((b & 31) + (kh << 5)) * 8 + e;
    hf[ho] = q0; hf[ho + 1024] = q1; hf[ho + 2048] = q2;
  }
}

// =======================================================================
// ------- fallback fp32 path (round-1, known-good; used if ws too small)
// =======================================================================
__global__ void tr_kernel(const float* __restrict__ src, float* __restrict__ dst,
                          int N, int dstride, int doff) {
  __shared__ float tile[32][33];
  int kb = blockIdx.y * 32, nb = blockIdx.x * 32;
  int tx = threadIdx.x, ty = threadIdx.y;
  for (int i = ty; i < 32; i += 8)
    tile[i][tx] = src[(size_t)(kb + i) * N + nb + tx];
  __syncthreads();
  for (int i = ty; i < 32; i += 8)
    dst[(size_t)(nb + i) * dstride + doff + kb + tx] = tile[tx][i];
}

__global__ __launch_bounds__(256)
void phase_fp32(int p, const int* __restrict__ idx,
                const float* __restrict__ EW0, const float* __restrict__ Wh0t,
                const float* __restrict__ W1t, const float* __restrict__ WoutT,
                const float* __restrict__ bias,
                float* __restrict__ h0, float* __restrict__ c0,
                float* __restrict__ h1, float* __restrict__ c1,
                float* __restrict__ out) {
  __shared__ float gl[64][17];
  const int bid = blockIdx.x, tid = threadIdx.x;
  const int sl_new = p & 1, sl_old = (p + 1) & 1;
  if (bid < 256) {
    if (p >= Tn) return;
    const int jbq = bid * 4;
    const int cg = tid & 15, rg = tid >> 4;
    const int g = cg >> 2, jo = cg & 3;
    const int col = g * Hn + jbq + jo;
    const int r0 = rg * 4;
    const float* h0o = h0 + sl_old * (Bn * Hn);
    const float4* wt = (const float4*)(Wh0t + (size_t)col * Hn);
    const float4* a0 = (const float4*)(h0o + (r0 + 0) * Hn);
    const float4* a1 = (const float4*)(h0o + (r0 + 1) * Hn);
    const float4* a2 = (const float4*)(h0o + (r0 + 2) * Hn);
    const float4* a3 = (const float4*)(h0o + (r0 + 3) * Hn);
    float s0 = 0, s1 = 0, s2 = 0, s3 = 0;
    for (int k = 0; k < Hn / 4; k++) {
      float4 ww = wt[k];
      float4 x0 = a0[k], x1 = a1[k], x2 = a2[k], x3 = a3[k];
      s0 = fmaf(x0.x, ww.x, s0); s0 = fmaf(x0.y, ww.y, s0); s0 = fmaf(x0.z, ww.z, s0); s0 = fmaf(x0.w, ww.w, s0);
      s1 = fmaf(x1.x, ww.x, s1); s1 = fmaf(x1.y, ww.y, s1); s1 = fmaf(x1.z, ww.z, s1); s1 = fmaf(x1.w, ww.w, s1);
      s2 = fmaf(x2.x, ww.x, s2); s2 = fmaf(x2.y, ww.y, s2); s2 = fmaf(x2.z, ww.z, s2); s2 = fmaf(x2.w, ww.w, s2);
      s3 = fmaf(x3.x, ww.x, s3); s3 = fmaf(x3.y, ww.y, s3); s3 = fmaf(x3.z, ww.z, s3); s3 = fmaf(x3.w, ww.w, s3);
    }
    float sv[4] = {s0, s1, s2, s3};
#pragma unroll
    for (int i = 0; i < 4; i++) {
      int r = r0 + i;
      int v = idx[r * Tn + p];
      gl[r][cg] = sv[i] + EW0[(size_t)v * Gn + col];
    }
    __syncthreads();
    {
      int r = tid & 63, jj = tid >> 6;
      int j = jbq + jj;
      float ig = gl[r][jj], fg = gl[r][4 + jj], gg = gl[r][8 + jj], og = gl[r][12 + jj];
      float cn = sigf(fg) * c0[r * Hn + j] + sigf(ig) * tanh_(gg);
      float hnv = sigf(og) * tanh_(cn);
      c0[r * Hn + j] = cn;
      h0[sl_new * (Bn * Hn) + r * Hn + j] = hnv;
    }
  } else if (bid < 768) {
    const int t = p - 1;
    if (t < 0 || t >= Tn) return;
    const int wg = bid - 256;
    const int jbq = wg * 2;
    const int cg = tid & 7, rg = tid >> 3;
    const int g = cg >> 1, jo = cg & 1;
    const int col = g * Hn + jbq + jo;
    const int r0 = rg * 2;
    const float* h0c = h0 + sl_old * (Bn * Hn);
    const float* h1o = h1 + sl_new * (Bn * Hn);
    const float4* wt = (const float4*)(W1t + (size_t)col * (2 * Hn));
    float s0 = 0, s1 = 0;
    {
      const float4* a0 = (const float4*)(h0c + (r0 + 0) * Hn);
      const float4* a1 = (const float4*)(h0c + (r0 + 1) * Hn);
      for (int k = 0; k < Hn / 4; k++) {
        float4 ww = wt[k];
        float4 x0 = a0[k], x1 = a1[k];
        s0 = fmaf(x0.x, ww.x, s0); s0 = fmaf(x0.y, ww.y, s0); s0 = fmaf(x0.z, ww.z, s0); s0 = fmaf(x0.w, ww.w, s0);
        s1 = fmaf(x1.x, ww.x, s1); s1 = fmaf(x1.y, ww.y, s1); s1 = fmaf(x1.z, ww.z, s1); s1 = fmaf(x1.w, ww.w, s1);
      }
    }
    {
      const float4* a0 = (const float4*)(h1o + (r0 + 0) * Hn);
      const float4* a1 = (const float4*)(h1o + (r0 + 1) * Hn);
      const float4* wt2 = wt + Hn / 4;
      for (int k = 0; k < Hn / 4; k++) {
        float4 ww = wt2[k];
        float4 x0 = a0[k], x1 = a1[k];
        s0 = fmaf(x0.x, ww.x, s0); s0 = fmaf(x0.y, ww.y, s0); s0 = fmaf(x0.z, ww.z, s0); s0 = fmaf(x0.w, ww.w, s0);
        s1 = fmaf(x1.x, ww.x, s1); s1 = fmaf(x1.y, ww.y, s1); s1 = fmaf(x1.z, ww.z, s1); s1 = fmaf(x1.w, ww.w, s1);
      }
    }
    float bb = bias[Gn + col];
    gl[r0][cg] = s0 + bb;
    gl[r0 + 1][cg] = s1 + bb;
    __syncthreads();
    if (tid < 128) {
      int r = tid & 63, jj = tid >> 6;
      int j = jbq + jj;
      float ig = gl[r][jj], fg = gl[r][2 + jj], gg = gl[r][4 + jj], og = gl[r][6 + jj];
      float cn = sigf(fg) * c1[r * Hn + j] + sigf(ig) * tanh_(gg);
      float hnv = sigf(og) * tanh_(cn);
      c1[r * Hn + j] = cn;
      h1[sl_old * (Bn * Hn) + r * Hn + j] = hnv;
    }
  } else {
    const int t = p - 2;
    if (t < 0 || t >= Tn) return;
    const int wg = bid - 768;
    const int cb = wg * 16;
    const int cg = tid & 15, rg = tid >> 4;
    const int col = cb + cg;
    const int r0 = rg * 4;
    const float* h1r = h1 + sl_new * (Bn * Hn);
    const float4* wt = (const float4*)(WoutT + (size_t)col * Hn);
    const float4* a0 = (const float4*)(h1r + (r0 + 0) * Hn);
    const float4* a1 = (const float4*)(h1r + (r0 + 1) * Hn);
    const float4* a2 = (const float4*)(h1r + (r0 + 2) * Hn);
    const float4* a3 = (const float4*)(h1r + (r0 + 3) * Hn);
    float s0 = 0, s1 = 0, s2 = 0, s3 = 0;
    for (int k = 0; k < Hn / 4; k++) {
      float4 ww = wt[k];
      float4 x0 = a0[k], x1 = a1[k], x2 = a2[k], x3 = a3[k];
      s0 = fmaf(x0.x, ww.x, s0); s0 = fmaf(x0.y, ww.y, s0); s0 = fmaf(x0.z, ww.z, s0); s0 = fmaf(x0.w, ww.w, s0);
      s1 = fmaf(x1.x, ww.x, s1); s1 = fmaf(x1.y, ww.y, s1); s1 = fmaf(x1.z, ww.z, s1); s1 = fmaf(x1.w, ww.w, s1);
      s2 = fmaf(x2.x, ww.x, s2); s2 = fmaf(x2.y, ww.y, s2); s2 = fmaf(x2.z, ww.z, s2); s2 = fmaf(x2.w, ww.w, s2);
      s3 = fmaf(x3.x, ww.x, s3); s3 = fmaf(x3.y, ww.y, s3); s3 = fmaf(x3.z, ww.z, s3); s3 = fmaf(x3.w, ww.w, s3);
    }
    float sv[4] = {s0, s1, s2, s3};
#pragma unroll
    for (int i = 0; i < 4; i++)
      out[((size_t)(r0 + i) * Tn + t) * Vn + col] = sv[i];
  }
}

// =======================================================================
extern "C" void kernel_launch(void* const* d_in, const int* in_sizes, int n_in,
                              void* d_out, int out_size, void* d_ws, size_t ws_size,
                              hipStream_t stream) {
  const int* idx = (const int*)d_in[0];        // (B,T) int32
  const float* embed = (const float*)d_in[1];  // (V,H)
  const float* Wx = (const float*)d_in[2];     // (L,H,4H)
  const float* Wh = (const float*)d_in[3];     // (L,H,4H)
  const float* bias = (const float*)d_in[4];   // (L,4H)
  const float* Wout = (const float*)d_in[5];   // (H,V)
  float* out = (float*)d_out;                  // (B,T,V) fp32

  const size_t REQ = 85983232ull;
  if (ws_size >= REQ) {
    // ---- MFMA split-bf16 path ----
    unsigned short* W0f = (unsigned short*)d_ws;        // 128nt x 64ks x 3 x 512
    unsigned short* W1f = W0f + 12582912;               // 128nt x 128ks x 3 x 512
    unsigned short* Woutf = W1f + 25165824;             // 4nt x 64ks x 3 x 512
    float* EW0 = (float*)(Woutf + 393216);              // 128 x 4096
    unsigned short* h0f = (unsigned short*)(EW0 + 524288);  // 64ks x 3 x 2 x 512
    unsigned short* h1f = h0f + 196608;
    float* c0t = (float*)(h1f + 196608);                // [j][b] 1024x64
    float* c1t = c0t + 65536;
    float* pa0 = c1t + 65536;                           // 32jb x 2seg x 64 x 128
    float* pa1 = pa0 + 524288;                          // 32jb x 4seg x 64 x 128

    hipMemsetAsync(h0f, 0, 1310720, stream);  // h0f,h1f,c0t,c1t

    pack_kernel<<<128 * 64, 64, 0, stream>>>(Wh, Wh, 1024, 64, Gn, 1, W0f);
    pack_kernel<<<128 * 128, 64, 0, stream>>>(Wx + (size_t)Hn * Gn, Wh + (size_t)Hn * Gn,
                                              1024, 128, Gn, 1, W1f);
    pack_kernel<<<4 * 64, 64, 0, stream>>>(Wout, Wout, 2048, 64, Vn, 0, Woutf);
    ew0_kernel<<<dim3(Gn / 256, Vn / 8), 256, 0, stream>>>(embed, Wx, bias, EW0);

    for (int p = 0; p < Tn + 2; p++) {
      gemm_phase<<<193, 256, 0, stream>>>(p, W0f, W1f, Woutf, h0f, h1f, pa0, pa1, out);
      if (p < Tn + 1)
        update_phase<<<64, 256, 0, stream>>>(p, idx, EW0, bias, pa0, pa1, h0f, h1f, c0t, c1t);
    }
  } else {
    // ---- fallback fp32 path (round-1) ----
    float* ws = (float*)d_ws;
    float* EW0 = ws;
    float* Wh0t = EW0 + 524288;
    float* W1t = Wh0t + 4194304;
    float* WoutT = W1t + 8388608;
    float* h0 = WoutT + 131072;
    float* h1 = h0 + 131072;
    float* c0 = h1 + 131072;
    float* c1 = c0 + 65536;
    hipMemsetAsync(h0, 0, (size_t)(131072 + 131072 + 65536 + 65536) * sizeof(float), stream);
    dim3 tb(32, 8);
    tr_kernel<<<dim3(Gn / 32, Hn / 32), tb, 0, stream>>>(Wh, Wh0t, Gn, Hn, 0);
    tr_kernel<<<dim3(Gn / 32, Hn / 32), tb, 0, stream>>>(Wx + (size_t)Hn * Gn, W1t, Gn, 2 * Hn, 0);
    tr_kernel<<<dim3(Gn / 32, Hn / 32), tb, 0, stream>>>(Wh + (size_t)Hn * Gn, W1t, Gn, 2 * Hn, Hn);
    tr_kernel<<<dim3(Vn / 32, Hn / 32), tb, 0, stream>>>(Wout, WoutT, Vn, Hn, 0);
    ew0_kernel<<<dim3(Gn / 256, Vn / 8), 256, 0, stream>>>(embed, Wx, bias, EW0);
    for (int p = 0; p < Tn + 2; p++)
      phase_fp32<<<776, 256, 0, stream>>>(p, idx, EW0, Wh0t, W1t, WoutT, bias,
                                          h0, c0, h1, c1, out);
  }
  (void)in_sizes; (void)n_in; (void)out_size; (void)ws_size;
}